// Round 9
// baseline (41.684 us; speedup 1.0000x reference)
//
#include <hip/hip_runtime.h>

#define TT 256
#define BB 256
#define DD 128
#define INV2PI 0.15915494309189535f
// out: outs[TT][BB][128] then hx[BB][128] then cx[BB][128]
// ws: A[t][b] float4 (1 MiB). After consumption, .x of A[t][b] = h_t(b), .y of A[255][b] = c(b).

__device__ __forceinline__ float frcp(float x) { return __builtin_amdgcn_rcpf(x); }
// broadcast lane (quad_base+J) to all 4 lanes of each quad (pure-VALU DPP)
template<int J>
__device__ __forceinline__ float quad_bcast(float v) {
    int i = __float_as_int(v);
    return __int_as_float(__builtin_amdgcn_update_dpp(i, i, J * 0x55, 0xF, 0xF, false));
}

// Kernel 1: A[t*BB+b] = angles/(2pi): a_g = (x[t,b,:].Wg[0,0:128] + bg[0] + pg[0]) / 2pi
__global__ __launch_bounds__(256) void k_angles(
    const float* __restrict__ x,
    const float* __restrict__ Wf, const float* __restrict__ bf, const float* __restrict__ pf,
    const float* __restrict__ Wi, const float* __restrict__ bi, const float* __restrict__ pi,
    const float* __restrict__ Wu, const float* __restrict__ bu, const float* __restrict__ pu,
    const float* __restrict__ Wo, const float* __restrict__ bo, const float* __restrict__ po,
    float4* __restrict__ A)
{
    __shared__ float4 w4[4][32];             // row 0, cols 0..127 of each W, pre-scaled
    float* w = reinterpret_cast<float*>(w4);
    int tid = threadIdx.x;
    for (int k = tid; k < 512; k += 256) {
        int g = k >> 7, j = k & 127;
        const float* W = (g == 0) ? Wf : (g == 1) ? Wi : (g == 2) ? Wu : Wo;
        w[g * 128 + j] = W[j] * INV2PI;
    }
    __syncthreads();

    int r = blockIdx.x * 256 + tid;          // r = t*BB + b
    const float4* xr = reinterpret_cast<const float4*>(x + (size_t)r * DD);

    float af = (bf[0] + pf[0]) * INV2PI;
    float ai = (bi[0] + pi[0]) * INV2PI;
    float au = (bu[0] + pu[0]) * INV2PI;
    float ao = (bo[0] + po[0]) * INV2PI;
    #pragma unroll
    for (int k = 0; k < 32; ++k) {
        float4 v  = xr[k];
        float4 f4 = w4[0][k], i4 = w4[1][k], u4 = w4[2][k], o4 = w4[3][k];
        af = fmaf(v.x, f4.x, fmaf(v.y, f4.y, fmaf(v.z, f4.z, fmaf(v.w, f4.w, af))));
        ai = fmaf(v.x, i4.x, fmaf(v.y, i4.y, fmaf(v.z, i4.z, fmaf(v.w, i4.w, ai))));
        au = fmaf(v.x, u4.x, fmaf(v.y, u4.y, fmaf(v.z, u4.z, fmaf(v.w, u4.w, au))));
        ao = fmaf(v.x, o4.x, fmaf(v.y, o4.y, fmaf(v.z, o4.z, fmaf(v.w, o4.w, ao))));
    }
    A[r] = make_float4(af, ai, au, ao);      // coalesced [t][b] store
}

// Kernel 2: quad-per-sample recurrence. 16 blocks x 1 wave; lane=(q<<2)|g, quad q
// owns sample blk*16+q. In-loop vmem = LOADS ONLY (depth-8 scalar prefetch);
// h history goes to LDS (lgkmcnt pipe — never blocks the load waits).
// Tail copies LDS -> this block's own A slots (race-free by ownership).
__global__ __launch_bounds__(64) void k_recur(
    float* __restrict__ Af,                  // A as floats: (t*BB+s)*4 + g
    const float* __restrict__ Wf, const float* __restrict__ Wi,
    const float* __restrict__ Wu, const float* __restrict__ Wo)
{
    __shared__ float Hl[16 * 260];           // [sample_in_block][t], pad 260
    int lane = threadIdx.x;
    int q = lane >> 2, g = lane & 3;
    int s = blockIdx.x * 16 + q;
    int s4g = s * 4 + g;
    int hq = q * 260;                        // all 4 quad lanes write same addr (same value)

    // S_g = (sum Wg[0,128:256]) / 2pi (h constant over hidden dim -> scalar feedback)
    const float* W = (g == 0) ? Wf : (g == 1) ? Wi : (g == 2) ? Wu : Wo;
    const float4* W4 = reinterpret_cast<const float4*>(W + 128);
    float S = 0.f;
    #pragma unroll
    for (int k = 0; k < 32; ++k) {
        float4 v = W4[k];
        S += (v.x + v.y) + (v.z + v.w);
    }
    S *= INV2PI;

    // act = Bq + v*(Q0 + Q1*w + Q2*w^2), v = cos(2pi*z), w = v^2 — exact 3-harmonic
    // Fourier of sigma(cos)/tanh(cos). No rcp in the gate path.
    bool tg = (g == 2);
    float Q0 = tg ? 0.99702f   : 0.2500128f;
    float Q1 = tg ? -0.3074f   : -0.0207238f;
    float Q2 = tg ? 0.07232f   : 0.00176256f;
    float Bq = tg ? 0.f        : 0.5f;

    const float* Ab = Af + s4g;              // element t at Ab[t*1024]
    float h = 0.f, c = 0.f;

    // prefetch depth 8 (named regs; pure-load vmcnt queue)
    float p0 = Ab[0*1024], p1 = Ab[1*1024], p2 = Ab[2*1024], p3 = Ab[3*1024];
    float p4 = Ab[4*1024], p5 = Ab[5*1024], p6 = Ab[6*1024], p7 = Ab[7*1024];

#define STEPC(P)                                                              \
    {                                                                         \
        float z = fmaf(h, S, P);             /* revolutions, |z| < ~2 */      \
        float v = __builtin_amdgcn_cosf(z);                                   \
        float w = v * v;                                                      \
        float act = fmaf(v, fmaf(w, fmaf(w, Q2, Q1), Q0), Bq);                \
        float tu = quad_bcast<2>(act);                                        \
        float ti = quad_bcast<1>(act);                                        \
        float tf = quad_bcast<0>(act);                                        \
        float to = quad_bcast<3>(act);                                        \
        c = fmaf(tf, c, ti * tu);            /* |c| <= 2.08 */                \
        float w2 = c * c;                                                     \
        float d2 = fmaf(w2, fmaf(w2, w2 + 210.f, 4725.f), 10395.f);           \
        float rd2 = frcp(d2);                                                 \
        float n2 = c * fmaf(w2, fmaf(w2, 21.f, 1260.f), 10395.f);             \
        h = (to * n2) * rd2;                                                  \
    }
#define STEP(P, TIDX) { STEPC(P); Hl[hq + (TIDX)] = h; }

    for (int t = 0; t < TT - 8; t += 8) {    // t = 0..240; prefetch tn+7 <= 255
        int tn = t + 8;
        STEP(p0, t + 0); p0 = Ab[(size_t)(tn + 0) * 1024];
        STEP(p1, t + 1); p1 = Ab[(size_t)(tn + 1) * 1024];
        STEP(p2, t + 2); p2 = Ab[(size_t)(tn + 2) * 1024];
        STEP(p3, t + 3); p3 = Ab[(size_t)(tn + 3) * 1024];
        STEP(p4, t + 4); p4 = Ab[(size_t)(tn + 4) * 1024];
        STEP(p5, t + 5); p5 = Ab[(size_t)(tn + 5) * 1024];
        STEP(p6, t + 6); p6 = Ab[(size_t)(tn + 6) * 1024];
        STEP(p7, t + 7); p7 = Ab[(size_t)(tn + 7) * 1024];
    }
    STEP(p0, 248) STEP(p1, 249) STEP(p2, 250) STEP(p3, 251)
    STEP(p4, 252) STEP(p5, 253) STEP(p6, 254) STEP(p7, 255)
#undef STEP
#undef STEPC

    __syncthreads();                         // drain ds_writes, cross-lane visibility

    // tail: Hl[sl][t] -> A.x of slot (t, blk*16+sl)  (own slots only -> race-free)
    int base_b = blockIdx.x * 16;
    for (int k = 0; k < 64; ++k) {
        int flat = k * 64 + lane;            // 0..4095
        int t  = flat & 255;
        int sl = flat >> 8;
        float hv = Hl[sl * 260 + t];
        Af[((size_t)t * 256 + base_b + sl) * 4] = hv;
    }
    if (g == 1) Af[((size_t)255 * 256 + s) * 4 + 1] = c;   // final c -> .y of (255,s)
}

// Kernel 3: broadcast expand. outs[t][b][:] = A[t][b].x; hx[b][:] = A[255][b].x;
// cx[b][:] = A[255][b].y
__global__ __launch_bounds__(256) void k_expand(
    const float* __restrict__ AT, float4* __restrict__ out)
{
    unsigned r = blockIdx.x * 256 + threadIdx.x;          // one float4 of output
    const unsigned OUTS4 = (unsigned)TT * BB * 128 / 4;   // 2,097,152
    const unsigned HX4   = (unsigned)BB * 128 / 4;        // 8,192
    float v;
    if (r < OUTS4) {
        unsigned t = r >> 13, b = (r >> 5) & 255u;
        v = AT[(t * 256u + b) * 4u];
    } else {
        unsigned qq = r - OUTS4;
        unsigned b = (qq & (HX4 - 1)) >> 5;
        v = (qq < HX4) ? AT[(255u * 256u + b) * 4u] : AT[(255u * 256u + b) * 4u + 1u];
    }
    out[r] = make_float4(v, v, v, v);
}

extern "C" void kernel_launch(void* const* d_in, const int* in_sizes, int n_in,
                              void* d_out, int out_size, void* d_ws, size_t ws_size,
                              hipStream_t stream) {
    const float* x = (const float*)d_in[0];
    const float *Wf, *bf, *pf, *Wi, *bi, *pi, *Wu, *bu, *pu, *Wo, *bo, *po;
    if (n_in >= 13 && in_sizes[3] == 8 && in_sizes[4] == 2048) {
        // setup_inputs dict order: (Wf,bf,pf),(Wi,bi,pi),(Wu,bu,pu),(Wo,bo,po)
        Wf = (const float*)d_in[1];  bf = (const float*)d_in[2];  pf = (const float*)d_in[3];
        Wi = (const float*)d_in[4];  bi = (const float*)d_in[5];  pi = (const float*)d_in[6];
        Wu = (const float*)d_in[7];  bu = (const float*)d_in[8];  pu = (const float*)d_in[9];
        Wo = (const float*)d_in[10]; bo = (const float*)d_in[11]; po = (const float*)d_in[12];
    } else {
        // reference signature order: Wf,bf,Wi,bi,Wu,bu,Wo,bo,pf,pi,pu,po
        Wf = (const float*)d_in[1];  bf = (const float*)d_in[2];
        Wi = (const float*)d_in[3];  bi = (const float*)d_in[4];
        Wu = (const float*)d_in[5];  bu = (const float*)d_in[6];
        Wo = (const float*)d_in[7];  bo = (const float*)d_in[8];
        pf = (const float*)d_in[9];  pi = (const float*)d_in[10];
        pu = (const float*)d_in[11]; po = (const float*)d_in[12];
    }
    float* A = (float*)d_ws;                   // 262144 floats = 1 MiB scratch

    k_angles<<<dim3(256), dim3(256), 0, stream>>>(
        x, Wf, bf, pf, Wi, bi, pi, Wu, bu, pu, Wo, bo, po, (float4*)A);
    k_recur<<<dim3(16), dim3(64), 0, stream>>>(A, Wf, Wi, Wu, Wo);
    k_expand<<<dim3((TT * BB * 128 / 4 + 2 * BB * 128 / 4) / 256), dim3(256), 0, stream>>>(
        A, (float4*)d_out);
}